// Round 9
// baseline (6295.227 us; speedup 1.0000x reference)
//
#include <hip/hip_runtime.h>
#include <hip/hip_bf16.h>
#include <stdint.h>

// a3c_lstm_ga forward, MI355X. Float tensors f32 (bf16-rounded values), ints
// int32. Output f32: [critic(1), actor(4), hx_new(768), cx_new(768)].
// Bug-faithful: only attn[0] consumed -> one GRU scan.
//
// R9: 2-CU split scan. R6-R8 proved the single-CU MFMA issue floor is
// 1516 cyc/step (384 MFMAs/CU, M=2/16 matvec waste) with a ~1280-cyc
// irreducible serial bubble. Split N gate-aligned: block "A" (bid 0) owns
// elements 0-127 (its r/z/n rows = 24 MFMAs/wave... 3 tiles x 8 K), block
// "B" (bid 8; 0/8 pairing targets same-XCD round-robin) owns 128-255.
// Per-SIMD MFMA floor halves to 768 cyc. Cross-block h exchange per step:
// packed hi|lo u32 agent-scope stores + per-wave release fetch_add flag;
// partner acquire-polls (guard-bounded, no hang) then agent-loads + v_perm
// unpacks into A-frags. Local-K MFMAs run before the poll to hide latency.
// h rides A rows 0/1 (hi, (h-hi)*1024); y = D[0][n] + D[1][n]/1024.
// Conv tower runs as block 1 of the same kernel; W-pack fused into init.

typedef _Float16 half8 __attribute__((ext_vector_type(8)));
typedef _Float16 half2v __attribute__((ext_vector_type(2)));
typedef float f32x4 __attribute__((ext_vector_type(4)));

__device__ __forceinline__ float sigm(float x) { return 1.0f / (1.0f + __expf(-x)); }
__device__ __forceinline__ float tanh_f(float x) { return 2.0f / (1.0f + __expf(-2.0f * x)) - 1.0f; }
__device__ __forceinline__ uint32_t pk(float a, float b) {
    half2v h = {(_Float16)a, (_Float16)b};
    return __builtin_bit_cast(uint32_t, h);
}
#define AL(p) __hip_atomic_load((p), __ATOMIC_RELAXED, __HIP_MEMORY_SCOPE_AGENT)

// ---------------- GRU input-gate precompute (+ b_hh fold for r,z rows) ---------
__global__ void k_gi(const int* __restrict__ curr, const float* __restrict__ emb,
                     const float* __restrict__ wih, const float* __restrict__ bih,
                     const float* __restrict__ bhh, float* __restrict__ gi) {
    int idx = blockIdx.x * 256 + threadIdx.x;  // 2048*768
    int j = idx % 768, t = idx / 768;
    int tok = curr[t];
    const float4* e = (const float4*)(emb + tok * 32);
    const float4* wr = (const float4*)(wih + j * 32);
    float acc = bih[j] + (j < 512 ? bhh[j] : 0.0f);  // n-row bias NOT additive (r*b)
#pragma unroll
    for (int k = 0; k < 8; ++k) {
        float4 ev = e[k], wv = wr[k];
        acc = fmaf(ev.x, wv.x, acc);
        acc = fmaf(ev.y, wv.y, acc);
        acc = fmaf(ev.z, wv.z, acc);
        acc = fmaf(ev.w, wv.w, acc);
    }
    gi[idx] = acc;
}

// ---------------- fused scan (blocks 0,8) + conv tower (block 1) ----------------
#define FORKT(X) X(0) X(1) X(2) X(3) X(4) X(5) X(6) X(7)
#define DECLB(kt) uint4 bR_##kt, bZ_##kt, bN_##kt;
#define PACK1(dst, rp, kt)                                        \
    {                                                             \
        float4 fA = *(const float4*)((rp) + (kt) * 32 + quad * 8);     \
        float4 fB = *(const float4*)((rp) + (kt) * 32 + quad * 8 + 4); \
        dst.x = pk(fA.x, fA.y); dst.y = pk(fA.z, fA.w);           \
        dst.z = pk(fB.x, fB.y); dst.w = pk(fB.z, fB.w);           \
    }
#define PACKB(kt) PACK1(bR_##kt, rpR, kt) PACK1(bZ_##kt, rpZ, kt) PACK1(bN_##kt, rpN, kt)
#define TIE1(v) asm volatile("" : "+v"(v.x), "+v"(v.y), "+v"(v.z), "+v"(v.w));
#define TIEB(kt) TIE1(bR_##kt) TIE1(bZ_##kt) TIE1(bN_##kt)
#define MFT(kt, areg)                                                                                        \
    accR = __builtin_amdgcn_mfma_f32_16x16x32_f16(areg, __builtin_bit_cast(half8, bR_##kt), accR, 0, 0, 0); \
    accZ = __builtin_amdgcn_mfma_f32_16x16x32_f16(areg, __builtin_bit_cast(half8, bZ_##kt), accZ, 0, 0, 0); \
    accN = __builtin_amdgcn_mfma_f32_16x16x32_f16(areg, __builtin_bit_cast(half8, bN_##kt), accN, 0, 0, 0);
#define RLOAD(i, base)                                                                              \
    uint32_t q##i##0 = AL((base) + 0), q##i##1 = AL((base) + 1), q##i##2 = AL((base) + 2),          \
             q##i##3 = AL((base) + 3), q##i##4 = AL((base) + 4), q##i##5 = AL((base) + 5),          \
             q##i##6 = AL((base) + 6), q##i##7 = AL((base) + 7);
#define RPERM(i)                                              \
    half8 ra##i;                                              \
    {                                                         \
        uint4 t;                                              \
        t.x = __builtin_amdgcn_perm(q##i##1, q##i##0, sel);   \
        t.y = __builtin_amdgcn_perm(q##i##3, q##i##2, sel);   \
        t.z = __builtin_amdgcn_perm(q##i##5, q##i##4, sel);   \
        t.w = __builtin_amdgcn_perm(q##i##7, q##i##6, sel);   \
        ra##i = __builtin_bit_cast(half8, t);                 \
    }

__global__ __attribute__((amdgpu_flat_work_group_size(512, 512), amdgpu_waves_per_eu(2, 2)))
void k_scan(const float* __restrict__ gi, const float* __restrict__ whh,
            const float* __restrict__ bhh, const float* __restrict__ attn_w,
            const float* __restrict__ attn_b, float* __restrict__ attn0,
            uint32_t* __restrict__ hrem, int* __restrict__ flags,
            const float* __restrict__ x, const float* __restrict__ c1w,
            const float* __restrict__ c1b, const float* __restrict__ c2w,
            const float* __restrict__ c2b, const float* __restrict__ c3w,
            const float* __restrict__ c3b, float* __restrict__ h1,
            float* __restrict__ h2, float* __restrict__ x3) {
    const int bid = blockIdx.x;
    const int tid = threadIdx.x;  // 0..511

    if (bid == 1) {
        // ---- conv tower, one block, hidden under the scan ----
        for (int it = 0; it < 225; ++it) {  // conv1: 128*30*30 = 225*512
            int idx = it * 512 + tid;
            int ox = idx % 30, oy = (idx / 30) % 30, oc = idx / 900;
            const float* wr = c1w + oc * 192;
            float acc = c1b[oc];
            for (int c = 0; c < 3; ++c)
                for (int ky = 0; ky < 8; ++ky) {
                    const float* xr = x + (c * 124 + oy * 4 + ky) * 124 + ox * 4;
                    const float* wk = wr + (c * 8 + ky) * 8;
#pragma unroll
                    for (int kx = 0; kx < 8; ++kx) acc = fmaf(xr[kx], wk[kx], acc);
                }
            h1[idx] = fmaxf(acc, 0.0f);
        }
        __syncthreads();
        for (int it = 0; it < 25; ++it) {  // conv2: 64*14*14 = 12544
            int idx = it * 512 + tid;
            if (idx < 12544) {
                int ox = idx % 14, oy = (idx / 14) % 14, oc = idx / 196;
                float acc = c2b[oc];
                const float* wr = c2w + oc * 128 * 16;
                for (int c = 0; c < 128; ++c) {
#pragma unroll
                    for (int ky = 0; ky < 4; ++ky) {
                        const float* hr = h1 + (c * 30 + oy * 2 + ky) * 30 + ox * 2;
                        const float* wk = wr + (c * 4 + ky) * 4;
#pragma unroll
                        for (int kx = 0; kx < 4; ++kx) acc = fmaf(hr[kx], wk[kx], acc);
                    }
                }
                h2[idx] = fmaxf(acc, 0.0f);
            }
        }
        __syncthreads();
        for (int it = 0; it < 5; ++it) {  // conv3: 64*6*6 = 2304
            int idx = it * 512 + tid;
            if (idx < 2304) {
                int ox = idx % 6, oy = (idx / 6) % 6, oc = idx / 36;
                float acc = c3b[oc];
                const float* wr = c3w + oc * 64 * 16;
                for (int c = 0; c < 64; ++c) {
#pragma unroll
                    for (int ky = 0; ky < 4; ++ky) {
                        const float* hr = h2 + (c * 14 + oy * 2 + ky) * 14 + ox * 2;
                        const float* wk = wr + (c * 4 + ky) * 4;
#pragma unroll
                        for (int kx = 0; kx < 4; ++kx) acc = fmaf(hr[kx], wk[kx], acc);
                    }
                }
                x3[idx] = fmaxf(acc, 0.0f);
            }
        }
        return;
    }
    if (bid != 0 && bid != 8) return;  // filler blocks (XCD round-robin spacing)

    // ---- scan half ----
    const int half = (bid == 0) ? 0 : 1;
    const int eb = half * 128;
    const int lane = tid & 63;
    const int wv = tid >> 6;     // wave 0..7, owns elements eb + wv*16 .. +16
    const int n16 = lane & 15;   // B row-in-tile; A row m; gate col
    const int quad = lane >> 4;  // k-subchunk
    const int myel = eb + wv * 16 + n16;
    const int rbase = (1 - half) * 4;  // remote K-tile base

    // local h double-buffer: parity p at [p*256, +256) f16; chunk c = hi[32]+lo[32]
    __shared__ __align__(16) _Float16 hbuf[512];

    // pack B-frags from f32 W_hh (f16 exact for bf16-rounded data)
    FORKT(DECLB)
    {
        const float* rpR = whh + (size_t)myel * 256;
        const float* rpZ = whh + (size_t)(256 + myel) * 256;
        const float* rpN = whh + (size_t)(512 + myel) * 256;
        FORKT(PACKB)
    }
    FORKT(TIEB)
    const float bn = bhh[512 + myel];

    if (tid == 0) __hip_atomic_store(&flags[half], 0, __ATOMIC_RELAXED, __HIP_MEMORY_SCOPE_AGENT);
    hbuf[tid] = (_Float16)0.0f;  // both parities (512 f16)
    if (lane < 16)               // publish h(0) = 0 (parity 0)
        __hip_atomic_store(&hrem[myel], 0u, __ATOMIC_RELAXED, __HIP_MEMORY_SCOPE_AGENT);
    float gr = 0.f, gz = 0.f, gn = 0.f, h = 0.f;
    if (lane < 16) {
        gr = gi[myel]; gz = gi[256 + myel]; gn = gi[512 + myel];
    }
    __syncthreads();
    if (lane == 0) __hip_atomic_fetch_add(&flags[half], 1, __ATOMIC_RELEASE, __HIP_MEMORY_SCOPE_AGENT);

    const uint32_t sel = (n16 == 1) ? 0x07060302u : 0x05040100u;  // lo-row lanes pick h_lo

#pragma clang loop unroll(disable)
    for (int s = 0; s < 2048; ++s) {
        const int par = s & 1;
        // local A-frags (broadcast addressing: only m==1 differs)
        const uint4* ab = (const uint4*)hbuf + par * 32 + ((n16 == 1) ? 4 : 0);
        half8 aA = __builtin_bit_cast(half8, ab[0 * 8 + quad]);
        half8 aB = __builtin_bit_cast(half8, ab[1 * 8 + quad]);
        half8 aC = __builtin_bit_cast(half8, ab[2 * 8 + quad]);
        half8 aD = __builtin_bit_cast(half8, ab[3 * 8 + quad]);

        // gi prefetch early so the release-add's vmcnt drain doesn't stall on it
        float pgr = 0.f, pgz = 0.f, pgn = 0.f;
        if (s < 2047 && lane < 16) {
            const float* gp = gi + (size_t)(s + 1) * 768 + myel;
            pgr = gp[0]; pgz = gp[256]; pgn = gp[512];
        }

        f32x4 accR = (f32x4)(0.0f), accZ = (f32x4)(0.0f), accN = (f32x4)(0.0f);
        // 12 local-K MFMAs first (no cross-block dependency) to hide sync latency
        if (half == 0) { MFT(0, aA) MFT(1, aB) MFT(2, aC) MFT(3, aD) }
        else          { MFT(4, aA) MFT(5, aB) MFT(6, aC) MFT(7, aD) }

        // poll partner for h(s) remote half (guard-bounded: no hang possible)
        {
            const int tgt = 8 * (s + 1);
            int g = 0;
            while (__hip_atomic_load(&flags[1 - half], __ATOMIC_ACQUIRE,
                                     __HIP_MEMORY_SCOPE_AGENT) < tgt && g < 3000) ++g;
        }
        // remote h: 32 agent-scope u32 loads -> v_perm unpack -> 4 A-frags
        const uint32_t* hr0 = hrem + par * 256 + rbase * 32 + quad * 8;
        RLOAD(0, hr0) RLOAD(1, hr0 + 32) RLOAD(2, hr0 + 64) RLOAD(3, hr0 + 96)
        RPERM(0) RPERM(1) RPERM(2) RPERM(3)
        if (half == 0) { MFT(4, ra0) MFT(5, ra1) MFT(6, ra2) MFT(7, ra3) }
        else          { MFT(0, ra0) MFT(1, ra1) MFT(2, ra2) MFT(3, ra3) }

        // gates: one element per lane (lanes 0-15 of every wave)
        if (lane < 16) {
            const float SC = 0.0009765625f;  // 2^-10
            float yr = fmaf(accR.y, SC, accR.x);
            float yz = fmaf(accZ.y, SC, accZ.x);
            float yn = fmaf(accN.y, SC, accN.x) + bn;
            float r = sigm(gr + yr);
            float z = sigm(gz + yz);
            float n = tanh_f(fmaf(r, yn, gn));
            h = fmaf(z, h - n, n);  // (1-z)*n + z*h
            _Float16 hh = (_Float16)h;
            _Float16 hl = (_Float16)((h - (float)hh) * 1024.0f);
            int cl = (myel >> 5) - half * 4, i = myel & 31;
            int wb = (par ^ 1) * 256 + cl * 64 + i;
            hbuf[wb] = hh;
            hbuf[wb + 32] = hl;
            uint32_t pkv = (uint32_t)__builtin_bit_cast(unsigned short, hh) |
                           ((uint32_t)__builtin_bit_cast(unsigned short, hl) << 16);
            __hip_atomic_store(&hrem[(par ^ 1) * 256 + myel], pkv, __ATOMIC_RELAXED,
                               __HIP_MEMORY_SCOPE_AGENT);
        }
        gr = pgr; gz = pgz; gn = pgn;
        if (lane == 0)
            __hip_atomic_fetch_add(&flags[half], 1, __ATOMIC_RELEASE, __HIP_MEMORY_SCOPE_AGENT);
        __syncthreads();
    }

    // attention head on block 0: attn0[j] = sigm(attn_w[j].h + attn_b[j]), j<64
    if (half == 0) {
        {   // wait for partner's final publish of h(2048)
            int g = 0;
            while (__hip_atomic_load(&flags[1], __ATOMIC_ACQUIRE,
                                     __HIP_MEMORY_SCOPE_AGENT) < 8 * 2049 && g < 3000) ++g;
        }
        if (tid < 64) {
            const float* ar = attn_w + tid * 256;
            float acc = attn_b[tid];
            for (int k = 0; k < 128; ++k) {  // local half from LDS (parity 0)
                int c = k >> 5, i = k & 31;
                float hk = (float)hbuf[c * 64 + i] + (float)hbuf[c * 64 + 32 + i] * 0.0009765625f;
                acc = fmaf(ar[k], hk, acc);
            }
            for (int k = 128; k < 256; ++k) {  // remote half via agent loads
                uint32_t v = AL(&hrem[k]);
                float hk = (float)__builtin_bit_cast(_Float16, (unsigned short)(v & 0xffffu)) +
                           (float)__builtin_bit_cast(_Float16, (unsigned short)(v >> 16)) * 0.0009765625f;
                acc = fmaf(ar[k], hk, acc);
            }
            attn0[tid] = sigm(acc);
        }
    }
}

// ---------------- fuse + linear ----------------
__global__ void k_feat(const float* __restrict__ x3, const float* __restrict__ attn0,
                       const float* __restrict__ lw, const float* __restrict__ lb,
                       float* __restrict__ feat) {
    __shared__ __align__(16) float fused[2304];
    int t = threadIdx.x;  // 64
    for (int i = t; i < 2304; i += 64) fused[i] = x3[i] * attn0[i / 36];
    __syncthreads();
    int row = blockIdx.x * 64 + t;
    const float4* wvv = (const float4*)(lw + (size_t)row * 2304);
    float acc = lb[row];
    for (int i = 0; i < 576; ++i) {
        float4 v = wvv[i];
        const float* f = fused + i * 4;
        acc = fmaf(v.x, f[0], acc);
        acc = fmaf(v.y, f[1], acc);
        acc = fmaf(v.z, f[2], acc);
        acc = fmaf(v.w, f[3], acc);
    }
    feat[row] = fmaxf(acc, 0.0f);
}

// ---------------- LSTM gates ----------------
__global__ void k_lstm_gates(const float* __restrict__ wih, const float* __restrict__ whh,
                             const float* __restrict__ bih, const float* __restrict__ bhh,
                             const float* __restrict__ hx, const float* __restrict__ feat,
                             float* __restrict__ gates) {
    int wid = threadIdx.x >> 6, lane = threadIdx.x & 63;
    int row = blockIdx.x * 4 + wid;
    const float* wi = wih + (size_t)row * 768;
    const float* wh = whh + (size_t)row * 768;
    float acc = 0.0f;
#pragma unroll
    for (int i = 0; i < 12; ++i) {
        int k = lane + i * 64;
        acc = fmaf(wi[k], feat[k & 255], acc);
        acc = fmaf(wh[k], hx[k], acc);
    }
#pragma unroll
    for (int s = 32; s; s >>= 1) acc += __shfl_down(acc, s, 64);
    if (lane == 0) gates[row] = acc + bih[row] + bhh[row];
}

// ---------------- LSTM cell ----------------
__global__ void k_lstm_cell(const float* __restrict__ gates, const float* __restrict__ cx,
                            float* __restrict__ out, float* __restrict__ hxf) {
    int i = threadIdx.x;  // 768
    float g_i = gates[i], g_f = gates[768 + i], g_g = gates[1536 + i], g_o = gates[2304 + i];
    float c = cx[i];
    float cn = sigm(g_f) * c + sigm(g_i) * tanh_f(g_g);
    float hn = sigm(g_o) * tanh_f(cn);
    out[5 + i] = hn;
    out[5 + 768 + i] = cn;
    hxf[i] = hn;
}

// ---------------- heads ----------------
__global__ void k_heads(const float* __restrict__ hxf, const float* __restrict__ temb,
                        const int* __restrict__ tx, const float* __restrict__ cw,
                        const float* __restrict__ cb, const float* __restrict__ aw,
                        const float* __restrict__ ab, float* __restrict__ out) {
    __shared__ float z[800];
    int t = threadIdx.x;  // 320
    for (int i = t; i < 768; i += 320) z[i] = hxf[i];
    if (t < 32) z[768 + t] = temb[tx[0] * 32 + t];
    __syncthreads();
    int w = t >> 6, lane = t & 63;
    const float* row = (w == 0) ? cw : (aw + (size_t)(w - 1) * 800);
    float acc = 0.0f;
    for (int k = lane; k < 800; k += 64) acc = fmaf(row[k], z[k], acc);
#pragma unroll
    for (int s = 32; s; s >>= 1) acc += __shfl_down(acc, s, 64);
    if (lane == 0) {
        float b = (w == 0) ? cb[0] : ab[w - 1];
        out[w] = acc + b;
    }
}

extern "C" void kernel_launch(void* const* d_in, const int* in_sizes, int n_in,
                              void* d_out, int out_size, void* d_ws, size_t ws_size,
                              hipStream_t stream) {
    const float* x = (const float*)d_in[0];
    const int* curr = (const int*)d_in[1];
    const int* tx = (const int*)d_in[4];
    const float* hx = (const float*)d_in[5];
    const float* cx = (const float*)d_in[6];
    const float* c1w = (const float*)d_in[7];
    const float* c1b = (const float*)d_in[8];
    const float* c2w = (const float*)d_in[9];
    const float* c2b = (const float*)d_in[10];
    const float* c3w = (const float*)d_in[11];
    const float* c3b = (const float*)d_in[12];
    const float* emb = (const float*)d_in[13];
    const float* temb = (const float*)d_in[14];
    const float* gwih = (const float*)d_in[15];
    const float* gwhh = (const float*)d_in[16];
    const float* gbih = (const float*)d_in[17];
    const float* gbhh = (const float*)d_in[18];
    const float* attw = (const float*)d_in[19];
    const float* attb = (const float*)d_in[20];
    const float* linw = (const float*)d_in[21];
    const float* linb = (const float*)d_in[22];
    const float* lwih = (const float*)d_in[23];
    const float* lwhh = (const float*)d_in[24];
    const float* lbih = (const float*)d_in[25];
    const float* lbhh = (const float*)d_in[26];
    const float* cw = (const float*)d_in[27];
    const float* cb = (const float*)d_in[28];
    const float* aw = (const float*)d_in[29];
    const float* ab = (const float*)d_in[30];
    float* out = (float*)d_out;

    char* ws = (char*)d_ws;
    float* gi = (float*)(ws + 0);            // 2048*768 f32
    float* h1 = (float*)(ws + 6291456);
    float* h2 = (float*)(ws + 6752256);
    float* x3 = (float*)(ws + 6802432);
    float* attn0 = (float*)(ws + 6811648);
    float* feat = (float*)(ws + 6811904);
    float* gates = (float*)(ws + 6812928);
    float* hxf = (float*)(ws + 6825216);
    uint32_t* hrem = (uint32_t*)(ws + 6828288);  // 2 parity x 256 u32 (hi|lo h)
    int* flags = (int*)(ws + 6830336);           // 2 publish counters

    k_gi<<<6144, 256, 0, stream>>>(curr, emb, gwih, gbih, gbhh, gi);
    k_scan<<<10, 512, 0, stream>>>(gi, gwhh, gbhh, attw, attb, attn0, hrem, flags,
                                   x, c1w, c1b, c2w, c2b, c3w, c3b, h1, h2, x3);
    k_feat<<<4, 64, 0, stream>>>(x3, attn0, linw, linb, feat);
    k_lstm_gates<<<768, 256, 0, stream>>>(lwih, lwhh, lbih, lbhh, hx, feat, gates);
    k_lstm_cell<<<1, 768, 0, stream>>>(gates, cx, out, hxf);
    k_heads<<<1, 320, 0, stream>>>(hxf, temb, tx, cw, cb, aw, ab, out);
}

// Round 10
// 4686.101 us; speedup vs baseline: 1.3434x; 1.3434x over previous
//
#include <hip/hip_runtime.h>
#include <hip/hip_bf16.h>
#include <stdint.h>

// a3c_lstm_ga forward, MI355X. Float tensors f32 (bf16-rounded values), ints
// int32. Output f32: [critic(1), actor(4), hx_new(768), cx_new(768)].
// Bug-faithful: only attn[0] consumed -> one GRU scan.
//
// R10: HYBRID-PIPE scan on ONE CU. Measured fact (R5-R8): per SIMD, MFMA at
// M=2/16 gives ~64 useful MAC/cyc == VALU v_dot2_f32_f16 rate. R6-R8 left
// the VALU pipe idle. Now: 8 waves / 2 per SIMD; waves 0-3 = MFMA path for
// elements 0-127 (48 MFMAs/wave -> 768 cyc/SIMD, half the old floor);
// waves 4-7 = dot2 path for elements 128-255 (thread: full r/z row + half
// n-row, K-chunked vs LDS h). One shared set of 48 named uint4 regs serves
// as B-frags (MFMA waves) or weight rows (VALU waves) -> single 192-reg
// static allocation, fits the 256 budget (R6-proven). R8 gate-aligned
// in-register gates, 1 barrier/step, parity-double-buffered hbuf.
// h rides hi/lo f16 (lo scaled 2^10); y = hi + lo*2^-10. R9's per-step
// cross-CU sync (WRITE_SIZE 3.5 MB, ~4400 cyc/step exposure) reverted.

typedef _Float16 half8 __attribute__((ext_vector_type(8)));
typedef _Float16 half2v __attribute__((ext_vector_type(2)));
typedef float f32x4 __attribute__((ext_vector_type(4)));

__device__ __forceinline__ float sigm(float x) { return 1.0f / (1.0f + __expf(-x)); }
__device__ __forceinline__ float tanh_f(float x) { return 2.0f / (1.0f + __expf(-2.0f * x)) - 1.0f; }
__device__ __forceinline__ uint32_t pk(float a, float b) {
    half2v h = {(_Float16)a, (_Float16)b};
    return __builtin_bit_cast(uint32_t, h);
}
#if __has_builtin(__builtin_amdgcn_fdot2)
__device__ __forceinline__ float dot2(uint32_t w, uint32_t h, float acc) {
    return __builtin_amdgcn_fdot2(__builtin_bit_cast(half2v, w),
                                  __builtin_bit_cast(half2v, h), acc, false);
}
#else
__device__ __forceinline__ float dot2(uint32_t w, uint32_t h, float acc) {
    half2v wv = __builtin_bit_cast(half2v, w), hv = __builtin_bit_cast(half2v, h);
    return fmaf((float)wv.y, (float)hv.y, fmaf((float)wv.x, (float)hv.x, acc));
}
#endif

// ---------------- GRU input-gate precompute (+ b_hh fold for r,z rows) ---------
__global__ void k_gi(const int* __restrict__ curr, const float* __restrict__ emb,
                     const float* __restrict__ wih, const float* __restrict__ bih,
                     const float* __restrict__ bhh, float* __restrict__ gi) {
    int idx = blockIdx.x * 256 + threadIdx.x;  // 2048*768
    int j = idx % 768, t = idx / 768;
    int tok = curr[t];
    const float4* e = (const float4*)(emb + tok * 32);
    const float4* wr = (const float4*)(wih + j * 32);
    float acc = bih[j] + (j < 512 ? bhh[j] : 0.0f);  // n-row bias NOT additive (r*b)
#pragma unroll
    for (int k = 0; k < 8; ++k) {
        float4 ev = e[k], wv = wr[k];
        acc = fmaf(ev.x, wv.x, acc);
        acc = fmaf(ev.y, wv.y, acc);
        acc = fmaf(ev.z, wv.z, acc);
        acc = fmaf(ev.w, wv.w, acc);
    }
    gi[idx] = acc;
}

// ---------------- unified weight registers: 48 named uint4 --------------------
#define REPU(X) X(0) X(1) X(2) X(3) X(4) X(5) X(6) X(7) X(8) X(9) X(10) X(11)   \
    X(12) X(13) X(14) X(15) X(16) X(17) X(18) X(19) X(20) X(21) X(22) X(23)     \
    X(24) X(25) X(26) X(27) X(28) X(29) X(30) X(31) X(32) X(33) X(34) X(35)     \
    X(36) X(37) X(38) X(39) X(40) X(41) X(42) X(43) X(44) X(45) X(46) X(47)
#define DECLU(i) uint4 U##i;
#define TIEU(i) asm volatile("" : "+v"(U##i.x), "+v"(U##i.y), "+v"(U##i.z), "+v"(U##i.w));
#define PACK8(dst, p)                                  \
    {                                                  \
        float4 fA = *(const float4*)(p);               \
        float4 fB = *(const float4*)((p) + 4);         \
        dst.x = pk(fA.x, fA.y); dst.y = pk(fA.z, fA.w); \
        dst.z = pk(fB.x, fB.y); dst.w = pk(fB.z, fB.w); \
    }
// MFMA init: tile T (rows rp), frag kt = U(8T+kt) packs rp[kt*32 + quad*8 ..+8)
#define PACKT(u0, u1, u2, u3, u4, u5, u6, u7, rp)                        \
    PACK8(u0, (rp) + 0 * 32 + quad * 8) PACK8(u1, (rp) + 1 * 32 + quad * 8) \
    PACK8(u2, (rp) + 2 * 32 + quad * 8) PACK8(u3, (rp) + 3 * 32 + quad * 8) \
    PACK8(u4, (rp) + 4 * 32 + quad * 8) PACK8(u5, (rp) + 5 * 32 + quad * 8) \
    PACK8(u6, (rp) + 6 * 32 + quad * 8) PACK8(u7, (rp) + 7 * 32 + quad * 8)
#define MM(A, B, C) __builtin_amdgcn_mfma_f32_16x16x32_f16(A, __builtin_bit_cast(half8, B), C, 0, 0, 0)
#define MF6(A, u0, u1, u2, u3, u4, u5)                           \
    acc0 = MM(A, u0, acc0); acc1 = MM(A, u1, acc1);              \
    acc2 = MM(A, u2, acc2); acc3 = MM(A, u3, acc3);              \
    acc4 = MM(A, u4, acc4); acc5 = MM(A, u5, acc5);
// VALU chunk: A-frags A0..A3 vs hh/hl (all 32 elems), B-frags B0,B1 vs thread's K-half
#define CHUNK(cc, A0, A1, A2, A3, B0, B1)                                          \
    {                                                                              \
        uint4 hh0 = hb[cc * 8 + 0], hh1 = hb[cc * 8 + 1];                          \
        uint4 hh2 = hb[cc * 8 + 2], hh3 = hb[cc * 8 + 3];                          \
        uint4 hl0 = hb[cc * 8 + 4], hl1 = hb[cc * 8 + 5];                          \
        uint4 hl2 = hb[cc * 8 + 6], hl3 = hb[cc * 8 + 7];                          \
        uint4 bh0 = hb[cc * 8 + hoff], bh1 = hb[cc * 8 + hoff + 1];                \
        uint4 bl0 = hb[cc * 8 + hoff + 4], bl1 = hb[cc * 8 + hoff + 5];            \
        accAH = dot2(A0.x, hh0.x, accAH); accAH = dot2(A0.y, hh0.y, accAH);        \
        accAH = dot2(A0.z, hh0.z, accAH); accAH = dot2(A0.w, hh0.w, accAH);        \
        accAH = dot2(A1.x, hh1.x, accAH); accAH = dot2(A1.y, hh1.y, accAH);        \
        accAH = dot2(A1.z, hh1.z, accAH); accAH = dot2(A1.w, hh1.w, accAH);        \
        accAH = dot2(A2.x, hh2.x, accAH); accAH = dot2(A2.y, hh2.y, accAH);        \
        accAH = dot2(A2.z, hh2.z, accAH); accAH = dot2(A2.w, hh2.w, accAH);        \
        accAH = dot2(A3.x, hh3.x, accAH); accAH = dot2(A3.y, hh3.y, accAH);        \
        accAH = dot2(A3.z, hh3.z, accAH); accAH = dot2(A3.w, hh3.w, accAH);        \
        accAL = dot2(A0.x, hl0.x, accAL); accAL = dot2(A0.y, hl0.y, accAL);        \
        accAL = dot2(A0.z, hl0.z, accAL); accAL = dot2(A0.w, hl0.w, accAL);        \
        accAL = dot2(A1.x, hl1.x, accAL); accAL = dot2(A1.y, hl1.y, accAL);        \
        accAL = dot2(A1.z, hl1.z, accAL); accAL = dot2(A1.w, hl1.w, accAL);        \
        accAL = dot2(A2.x, hl2.x, accAL); accAL = dot2(A2.y, hl2.y, accAL);        \
        accAL = dot2(A2.z, hl2.z, accAL); accAL = dot2(A2.w, hl2.w, accAL);        \
        accAL = dot2(A3.x, hl3.x, accAL); accAL = dot2(A3.y, hl3.y, accAL);        \
        accAL = dot2(A3.z, hl3.z, accAL); accAL = dot2(A3.w, hl3.w, accAL);        \
        accBH = dot2(B0.x, bh0.x, accBH); accBH = dot2(B0.y, bh0.y, accBH);        \
        accBH = dot2(B0.z, bh0.z, accBH); accBH = dot2(B0.w, bh0.w, accBH);        \
        accBH = dot2(B1.x, bh1.x, accBH); accBH = dot2(B1.y, bh1.y, accBH);        \
        accBH = dot2(B1.z, bh1.z, accBH); accBH = dot2(B1.w, bh1.w, accBH);        \
        accBL = dot2(B0.x, bl0.x, accBL); accBL = dot2(B0.y, bl0.y, accBL);        \
        accBL = dot2(B0.z, bl0.z, accBL); accBL = dot2(B0.w, bl0.w, accBL);        \
        accBL = dot2(B1.x, bl1.x, accBL); accBL = dot2(B1.y, bl1.y, accBL);        \
        accBL = dot2(B1.z, bl1.z, accBL); accBL = dot2(B1.w, bl1.w, accBL);        \
    }

__global__ __attribute__((amdgpu_flat_work_group_size(512, 512), amdgpu_waves_per_eu(2, 2)))
void k_scan(const float* __restrict__ gi, const float* __restrict__ whh,
            const float* __restrict__ bhh, const float* __restrict__ attn_w,
            const float* __restrict__ attn_b, float* __restrict__ attn0,
            const float* __restrict__ x, const float* __restrict__ c1w,
            const float* __restrict__ c1b, const float* __restrict__ c2w,
            const float* __restrict__ c2b, const float* __restrict__ c3w,
            const float* __restrict__ c3b, float* __restrict__ h1,
            float* __restrict__ h2, float* __restrict__ x3) {
    const int bid = blockIdx.x;
    const int tid = threadIdx.x;  // 0..511

    if (bid == 1) {  // ---- conv tower on a second CU, hidden under the scan ----
        for (int it = 0; it < 225; ++it) {
            int idx = it * 512 + tid;
            int ox = idx % 30, oy = (idx / 30) % 30, oc = idx / 900;
            const float* wr = c1w + oc * 192;
            float acc = c1b[oc];
            for (int c = 0; c < 3; ++c)
                for (int ky = 0; ky < 8; ++ky) {
                    const float* xr = x + (c * 124 + oy * 4 + ky) * 124 + ox * 4;
                    const float* wk = wr + (c * 8 + ky) * 8;
#pragma unroll
                    for (int kx = 0; kx < 8; ++kx) acc = fmaf(xr[kx], wk[kx], acc);
                }
            h1[idx] = fmaxf(acc, 0.0f);
        }
        __syncthreads();
        for (int it = 0; it < 25; ++it) {
            int idx = it * 512 + tid;
            if (idx < 12544) {
                int ox = idx % 14, oy = (idx / 14) % 14, oc = idx / 196;
                float acc = c2b[oc];
                const float* wr = c2w + oc * 128 * 16;
                for (int c = 0; c < 128; ++c) {
#pragma unroll
                    for (int ky = 0; ky < 4; ++ky) {
                        const float* hr = h1 + (c * 30 + oy * 2 + ky) * 30 + ox * 2;
                        const float* wk = wr + (c * 4 + ky) * 4;
#pragma unroll
                        for (int kx = 0; kx < 4; ++kx) acc = fmaf(hr[kx], wk[kx], acc);
                    }
                }
                h2[idx] = fmaxf(acc, 0.0f);
            }
        }
        __syncthreads();
        for (int it = 0; it < 5; ++it) {
            int idx = it * 512 + tid;
            if (idx < 2304) {
                int ox = idx % 6, oy = (idx / 6) % 6, oc = idx / 36;
                float acc = c3b[oc];
                const float* wr = c3w + oc * 64 * 16;
                for (int c = 0; c < 64; ++c) {
#pragma unroll
                    for (int ky = 0; ky < 4; ++ky) {
                        const float* hr = h2 + (c * 14 + oy * 2 + ky) * 14 + ox * 2;
                        const float* wk = wr + (c * 4 + ky) * 4;
#pragma unroll
                        for (int kx = 0; kx < 4; ++kx) acc = fmaf(hr[kx], wk[kx], acc);
                    }
                }
                x3[idx] = fmaxf(acc, 0.0f);
            }
        }
        return;
    }

    // ---- hybrid scan, single block/CU ----
    const int lane = tid & 63;
    const int wv = tid >> 6;     // 0-3: MFMA waves (elems wv*32..+32); 4-7: dot2 waves
    const int n16 = lane & 15;
    const int quad = lane >> 4;
    const bool mfmaw = (wv < 4);

    // parity-double-buffered h: parity p at f16 [p*512,+512); chunk c = hi[32]+lo[32]
    __shared__ __align__(16) _Float16 hbuf[1024];

    REPU(DECLU)
    float gr0 = 0.f, gr1 = 0.f, gz0 = 0.f, gz1 = 0.f, gn0 = 0.f, gn1 = 0.f;
    float bn0 = 0.f, bn1 = 0.f;
    float h0 = 0.f, h1r = 0.f;
    const int hoff = ((lane >> 5) & 1) * 2;  // dot2 B K-half selector (uint4 units)

    if (mfmaw) {
        // 6 tiles: r(wv*32+n16), r(+16), z, z, n, n — frag kt = U(8T+kt)
        const float* rp0 = whh + (size_t)(wv * 32 + n16) * 256;
        const float* rp1 = whh + (size_t)(wv * 32 + 16 + n16) * 256;
        const float* rp2 = whh + (size_t)(256 + wv * 32 + n16) * 256;
        const float* rp3 = whh + (size_t)(256 + wv * 32 + 16 + n16) * 256;
        const float* rp4 = whh + (size_t)(512 + wv * 32 + n16) * 256;
        const float* rp5 = whh + (size_t)(512 + wv * 32 + 16 + n16) * 256;
        PACKT(U0, U1, U2, U3, U4, U5, U6, U7, rp0)
        PACKT(U8, U9, U10, U11, U12, U13, U14, U15, rp1)
        PACKT(U16, U17, U18, U19, U20, U21, U22, U23, rp2)
        PACKT(U24, U25, U26, U27, U28, U29, U30, U31, rp3)
        PACKT(U32, U33, U34, U35, U36, U37, U38, U39, rp4)
        PACKT(U40, U41, U42, U43, U44, U45, U46, U47, rp5)
        bn0 = bhh[512 + wv * 32 + n16];
        bn1 = bhh[512 + wv * 32 + 16 + n16];
        if (lane < 16) {
            const float* gp = gi + wv * 32 + n16;
            gr0 = gp[0]; gr1 = gp[16]; gz0 = gp[256]; gz1 = gp[272];
            gn0 = gp[512]; gn1 = gp[528];
        }
    } else {
        // dot2 wave: element e = 128 + (wv-4)*32 + (lane&31)
        const int e = 128 + (wv - 4) * 32 + (lane & 31);
        const int rowA = (lane < 32) ? e : (256 + e);  // r-row or z-row (full)
        const int ksub = (lane < 32) ? 0 : 16;         // n-row K-half
        const float* rowAp = whh + (size_t)rowA * 256;
        const float* rowNp = whh + (size_t)(512 + e) * 256;
#define PA(a) PACK8(U##a, rowAp + a * 8)
        PA(0) PA(1) PA(2) PA(3) PA(4) PA(5) PA(6) PA(7)
        PA(8) PA(9) PA(10) PA(11) PA(12) PA(13) PA(14) PA(15)
        PA(16) PA(17) PA(18) PA(19) PA(20) PA(21) PA(22) PA(23)
        PA(24) PA(25) PA(26) PA(27) PA(28) PA(29) PA(30) PA(31)
#define PB(b, c, q) PACK8(U##b, rowNp + (c) * 32 + ksub + (q) * 8)
        PB(32, 0, 0) PB(33, 0, 1) PB(34, 1, 0) PB(35, 1, 1)
        PB(36, 2, 0) PB(37, 2, 1) PB(38, 3, 0) PB(39, 3, 1)
        PB(40, 4, 0) PB(41, 4, 1) PB(42, 5, 0) PB(43, 5, 1)
        PB(44, 6, 0) PB(45, 6, 1) PB(46, 7, 0) PB(47, 7, 1)
        bn0 = bhh[512 + e];
        if (lane < 32) {
            const float* gp = gi + e;
            gr0 = gp[0]; gz0 = gp[256]; gn0 = gp[512];
        }
    }
    REPU(TIEU)  // pin packed weights in registers (cannot be rematerialized)

    hbuf[tid] = (_Float16)0.0f;
    hbuf[512 + tid] = (_Float16)0.0f;
    __syncthreads();

#pragma clang loop unroll(disable)
    for (int step = 0; step < 2048; ++step) {
        const int par = step & 1;
        const int wb = ((step + 1) & 1) * 512 + wv * 64;  // own chunk, next parity
        if (mfmaw) {
            const uint4* ab = (const uint4*)hbuf + par * 64 + ((n16 == 1) ? 4 : 0);
            half8 aA = __builtin_bit_cast(half8, ab[0 * 8 + quad]);
            half8 aB = __builtin_bit_cast(half8, ab[1 * 8 + quad]);
            float pr0 = 0.f, pr1 = 0.f, pz0 = 0.f, pz1 = 0.f, pn0 = 0.f, pn1 = 0.f;
            if (step < 2047 && lane < 16) {
                const float* gp = gi + (size_t)(step + 1) * 768 + wv * 32 + n16;
                pr0 = gp[0]; pr1 = gp[16]; pz0 = gp[256]; pz1 = gp[272];
                pn0 = gp[512]; pn1 = gp[528];
            }
            f32x4 acc0 = (f32x4)(0.f), acc1 = (f32x4)(0.f), acc2 = (f32x4)(0.f);
            f32x4 acc3 = (f32x4)(0.f), acc4 = (f32x4)(0.f), acc5 = (f32x4)(0.f);
            MF6(aA, U0, U8, U16, U24, U32, U40) aA = __builtin_bit_cast(half8, ab[2 * 8 + quad]);
            MF6(aB, U1, U9, U17, U25, U33, U41) aB = __builtin_bit_cast(half8, ab[3 * 8 + quad]);
            MF6(aA, U2, U10, U18, U26, U34, U42) aA = __builtin_bit_cast(half8, ab[4 * 8 + quad]);
            MF6(aB, U3, U11, U19, U27, U35, U43) aB = __builtin_bit_cast(half8, ab[5 * 8 + quad]);
            MF6(aA, U4, U12, U20, U28, U36, U44) aA = __builtin_bit_cast(half8, ab[6 * 8 + quad]);
            MF6(aB, U5, U13, U21, U29, U37, U45) aB = __builtin_bit_cast(half8, ab[7 * 8 + quad]);
            MF6(aA, U6, U14, U22, U30, U38, U46)
            MF6(aB, U7, U15, U23, U31, U39, U47)
            if (lane < 16) {
                const float SC = 0.0009765625f;  // 2^-10
                float yr0 = fmaf(acc0.y, SC, acc0.x);
                float yr1 = fmaf(acc1.y, SC, acc1.x);
                float yz0 = fmaf(acc2.y, SC, acc2.x);
                float yz1 = fmaf(acc3.y, SC, acc3.x);
                float yn0 = fmaf(acc4.y, SC, acc4.x) + bn0;
                float yn1 = fmaf(acc5.y, SC, acc5.x) + bn1;
                float r0 = sigm(gr0 + yr0), r1 = sigm(gr1 + yr1);
                float z0 = sigm(gz0 + yz0), z1 = sigm(gz1 + yz1);
                float n0 = tanh_f(fmaf(r0, yn0, gn0));
                float n1 = tanh_f(fmaf(r1, yn1, gn1));
                h0 = fmaf(z0, h0 - n0, n0);
                h1r = fmaf(z1, h1r - n1, n1);
                _Float16 h0h = (_Float16)h0, h1h = (_Float16)h1r;
                hbuf[wb + n16] = h0h;
                hbuf[wb + 32 + n16] = (_Float16)((h0 - (float)h0h) * 1024.0f);
                hbuf[wb + 16 + n16] = h1h;
                hbuf[wb + 48 + n16] = (_Float16)((h1r - (float)h1h) * 1024.0f);
            }
            gr0 = pr0; gr1 = pr1; gz0 = pz0; gz1 = pz1; gn0 = pn0; gn1 = pn1;
        } else {
            const uint4* hb = (const uint4*)hbuf + par * 64;
            float pr0 = 0.f, pz0 = 0.f, pn0 = 0.f;
            if (step < 2047 && lane < 32) {
                const float* gp = gi + (size_t)(step + 1) * 768 + 128 + (wv - 4) * 32 + lane;
                pr0 = gp[0]; pz0 = gp[256]; pn0 = gp[512];
            }
            float accAH = 0.f, accAL = 0.f, accBH = 0.f, accBL = 0.f;
            CHUNK(0, U0, U1, U2, U3, U32, U33)
            CHUNK(1, U4, U5, U6, U7, U34, U35)
            CHUNK(2, U8, U9, U10, U11, U36, U37)
            CHUNK(3, U12, U13, U14, U15, U38, U39)
            CHUNK(4, U16, U17, U18, U19, U40, U41)
            CHUNK(5, U20, U21, U22, U23, U42, U43)
            CHUNK(6, U24, U25, U26, U27, U44, U45)
            CHUNK(7, U28, U29, U30, U31, U46, U47)
            const float SC = 0.0009765625f;
            float ad = fmaf(accAL, SC, accAH);        // r-dot (lanes<32) / z-dot (>=32)
            float bd = fmaf(accBL, SC, accBH);        // half n-dot
            float zd = __shfl_xor(ad, 32);            // partner's A-dot
            float nd = bd + __shfl_xor(bd, 32);       // full n-dot
            if (lane < 32) {
                float r = sigm(gr0 + ad);
                float z = sigm(gz0 + zd);
                float n = tanh_f(fmaf(r, nd + bn0, gn0));
                h0 = fmaf(z, h0 - n, n);
                _Float16 hh = (_Float16)h0;
                hbuf[wb + lane] = hh;
                hbuf[wb + 32 + lane] = (_Float16)((h0 - (float)hh) * 1024.0f);
            }
            gr0 = pr0; gz0 = pz0; gn0 = pn0;
        }
        __syncthreads();
    }

    // attention head: attn0[j] = sigm(attn_w[j] . h + attn_b[j]), j<64 (parity 0)
    if (tid < 64) {
        const float* ar = attn_w + tid * 256;
        float acc = attn_b[tid];
        for (int k = 0; k < 256; ++k) {
            int c = k >> 5, i = k & 31;
            float hk = (float)hbuf[c * 64 + i] + (float)hbuf[c * 64 + 32 + i] * 0.0009765625f;
            acc = fmaf(ar[k], hk, acc);
        }
        attn0[tid] = sigm(acc);
    }
}

// ---------------- fuse + linear ----------------
__global__ void k_feat(const float* __restrict__ x3, const float* __restrict__ attn0,
                       const float* __restrict__ lw, const float* __restrict__ lb,
                       float* __restrict__ feat) {
    __shared__ __align__(16) float fused[2304];
    int t = threadIdx.x;  // 64
    for (int i = t; i < 2304; i += 64) fused[i] = x3[i] * attn0[i / 36];
    __syncthreads();
    int row = blockIdx.x * 64 + t;
    const float4* wvv = (const float4*)(lw + (size_t)row * 2304);
    float acc = lb[row];
    for (int i = 0; i < 576; ++i) {
        float4 v = wvv[i];
        const float* f = fused + i * 4;
        acc = fmaf(v.x, f[0], acc);
        acc = fmaf(v.y, f[1], acc);
        acc = fmaf(v.z, f[2], acc);
        acc = fmaf(v.w, f[3], acc);
    }
    feat[row] = fmaxf(acc, 0.0f);
}

// ---------------- LSTM gates ----------------
__global__ void k_lstm_gates(const float* __restrict__ wih, const float* __restrict__ whh,
                             const float* __restrict__ bih, const float* __restrict__ bhh,
                             const float* __restrict__ hx, const float* __restrict__ feat,
                             float* __restrict__ gates) {
    int wid = threadIdx.x >> 6, lane = threadIdx.x & 63;
    int row = blockIdx.x * 4 + wid;
    const float* wi = wih + (size_t)row * 768;
    const float* wh = whh + (size_t)row * 768;
    float acc = 0.0f;
#pragma unroll
    for (int i = 0; i < 12; ++i) {
        int k = lane + i * 64;
        acc = fmaf(wi[k], feat[k & 255], acc);
        acc = fmaf(wh[k], hx[k], acc);
    }
#pragma unroll
    for (int s = 32; s; s >>= 1) acc += __shfl_down(acc, s, 64);
    if (lane == 0) gates[row] = acc + bih[row] + bhh[row];
}

// ---------------- LSTM cell ----------------
__global__ void k_lstm_cell(const float* __restrict__ gates, const float* __restrict__ cx,
                            float* __restrict__ out, float* __restrict__ hxf) {
    int i = threadIdx.x;  // 768
    float g_i = gates[i], g_f = gates[768 + i], g_g = gates[1536 + i], g_o = gates[2304 + i];
    float c = cx[i];
    float cn = sigm(g_f) * c + sigm(g_i) * tanh_f(g_g);
    float hn = sigm(g_o) * tanh_f(cn);
    out[5 + i] = hn;
    out[5 + 768 + i] = cn;
    hxf[i] = hn;
}

// ---------------- heads ----------------
__global__ void k_heads(const float* __restrict__ hxf, const float* __restrict__ temb,
                        const int* __restrict__ tx, const float* __restrict__ cw,
                        const float* __restrict__ cb, const float* __restrict__ aw,
                        const float* __restrict__ ab, float* __restrict__ out) {
    __shared__ float z[800];
    int t = threadIdx.x;  // 320
    for (int i = t; i < 768; i += 320) z[i] = hxf[i];
    if (t < 32) z[768 + t] = temb[tx[0] * 32 + t];
    __syncthreads();
    int w = t >> 6, lane = t & 63;
    const float* row = (w == 0) ? cw : (aw + (size_t)(w - 1) * 800);
    float acc = 0.0f;
    for (int k = lane; k < 800; k += 64) acc = fmaf(row[k], z[k], acc);
#pragma unroll
    for (int s = 32; s; s >>= 1) acc += __shfl_down(acc, s, 64);
    if (lane == 0) {
        float b = (w == 0) ? cb[0] : ab[w - 1];
        out[w] = acc + b;
    }
}

extern "C" void kernel_launch(void* const* d_in, const int* in_sizes, int n_in,
                              void* d_out, int out_size, void* d_ws, size_t ws_size,
                              hipStream_t stream) {
    const float* x = (const float*)d_in[0];
    const int* curr = (const int*)d_in[1];
    const int* tx = (const int*)d_in[4];
    const float* hx = (const float*)d_in[5];
    const float* cx = (const float*)d_in[6];
    const float* c1w = (const float*)d_in[7];
    const float* c1b = (const float*)d_in[8];
    const float* c2w = (const float*)d_in[9];
    const float* c2b = (const float*)d_in[10];
    const float* c3w = (const float*)d_in[11];
    const float* c3b = (const float*)d_in[12];
    const float* emb = (const float*)d_in[13];
    const float* temb = (const float*)d_in[14];
    const float* gwih = (const float*)d_in[15];
    const float* gwhh = (const float*)d_in[16];
    const float* gbih = (const float*)d_in[17];
    const float* gbhh = (const float*)d_in[18];
    const float* attw = (const float*)d_in[19];
    const float* attb = (const float*)d_in[20];
    const float* linw = (const float*)d_in[21];
    const float* linb = (const float*)d_in[22];
    const float* lwih = (const float*)d_in[23];
    const float* lwhh = (const float*)d_in[24];
    const float* lbih = (const float*)d_in[25];
    const float* lbhh = (const float*)d_in[26];
    const float* cw = (const float*)d_in[27];
    const float* cb = (const float*)d_in[28];
    const float* aw = (const float*)d_in[29];
    const float* ab = (const float*)d_in[30];
    float* out = (float*)d_out;

    char* ws = (char*)d_ws;
    float* gi = (float*)(ws + 0);            // 2048*768 f32
    float* h1 = (float*)(ws + 6291456);
    float* h2 = (float*)(ws + 6752256);
    float* x3 = (float*)(ws + 6802432);
    float* attn0 = (float*)(ws + 6811648);
    float* feat = (float*)(ws + 6811904);
    float* gates = (float*)(ws + 6812928);
    float* hxf = (float*)(ws + 6825216);

    k_gi<<<6144, 256, 0, stream>>>(curr, emb, gwih, gbih, gbhh, gi);
    k_scan<<<2, 512, 0, stream>>>(gi, gwhh, gbhh, attw, attb, attn0,
                                  x, c1w, c1b, c2w, c2b, c3w, c3b, h1, h2, x3);
    k_feat<<<4, 64, 0, stream>>>(x3, attn0, linw, linb, feat);
    k_lstm_gates<<<768, 256, 0, stream>>>(lwih, lwhh, lbih, lbhh, hx, feat, gates);
    k_lstm_cell<<<1, 768, 0, stream>>>(gates, cx, out, hxf);
    k_heads<<<1, 320, 0, stream>>>(hxf, temb, tx, cw, cb, aw, ab, out);
}